// Round 16
// baseline (852.880 us; speedup 1.0000x reference)
//
#include <hip/hip_runtime.h>
#include <math.h>

#define N 256
#define Dd 128

__device__ __forceinline__ double inv2s2_of(int s){
    return (s==0)?0.5:(s==1)?5.0e-3:(s==2)?5.0e-5:5.0e-7;
}

// verified elementwise f64 GJ sweep of a 32x32 LDS tile (rounds 1/4/6/10-15).
// After: P = +D^{-1}. Executed by tid<64, wave-lockstep.
__device__ __forceinline__ void sweep32(double (*P)[33], int tid){
    if (tid < 64){
        int r = tid & 31, cg = tid >> 5;
        for (int j = 0; j < 32; j++){
            double d    = P[j][j];
            double invd = 1.0 / d;
            double cr   = P[r][j];
            double s    = cr * invd;
            bool rj = (r == j);
            double nv[16];
            #pragma unroll
            for (int c = 0; c < 16; c++){
                int col = cg*16 + c;
                double pj = P[j][col];
                double v  = P[r][col];
                nv[c] = rj ? ((col == j) ? -invd : v * invd)
                           : ((col == j) ? s : v - s*pj);
            }
            #pragma unroll
            for (int c = 0; c < 16; c++) P[r][cg*16+c] = nv[c];
        }
        #pragma unroll
        for (int c = 0; c < 16; c++) P[r][cg*16+c] = -P[r][cg*16+c];
    }
}

// 64x64 in-LDS inversion: 2x2-blocked sweep (two verified sweep32 passes +
// mini-GEMMs; symmetry row=C^T). T stride 66. After: T = swept = -inv(T).
__device__ void inv64(double* T, double (*P32)[33], double* C32, int tid){
    for (int s2 = 0; s2 < 2; s2++){
        int pb = s2*32, er = 32 - pb;
        #pragma unroll
        for (int l = 0; l < 4; l++){
            int e = tid + l*256;
            P32[e>>5][e&31] = T[(pb + (e>>5))*66 + pb + (e&31)];
        }
        __syncthreads();
        sweep32(P32, tid);          // P32 = inv(pivot)
        __syncthreads();
        #pragma unroll
        for (int l = 0; l < 4; l++){
            int e = tid + l*256; int r = e>>5, c = e&31;
            double acc = 0.0;
            #pragma unroll
            for (int kk = 0; kk < 32; kk++)
                acc += T[(er+r)*66 + pb+kk] * P32[kk][c];
            C32[r*33 + c] = acc;
        }
        __syncthreads();
        #pragma unroll
        for (int l = 0; l < 4; l++){
            int e = tid + l*256; int r = e>>5, c = e&31;
            double acc = T[(er+r)*66 + er+c];
            #pragma unroll
            for (int m = 0; m < 32; m++)
                acc -= T[(er+r)*66 + pb+m] * C32[c*33+m];
            T[(er+r)*66 + er+c] = acc;
        }
        __syncthreads();
        #pragma unroll
        for (int l = 0; l < 4; l++){
            int e = tid + l*256; int r = e>>5, c = e&31;
            T[(er+r)*66 + pb+c] = C32[r*33+c];
            T[(pb+r)*66 + er+c] = C32[c*33+r];
            T[(pb+r)*66 + pb+c] = -P32[r][c];
        }
        __syncthreads();
    }
}

// ------- fused gather + distances + kernel matrices + bnum partials ---------
__global__ void k_dist(const float* __restrict__ z1, const float* __restrict__ z2,
                       const int* __restrict__ p1, const int* __restrict__ p2,
                       double* __restrict__ S0, float* __restrict__ M4,
                       float* __restrict__ U4, double* __restrict__ bpart){
    __shared__ float Xs[16][17], Ys[16][17];
    int w = blockIdx.z;
    int tx = threadIdx.x, ty = threadIdx.y;
    int row = blockIdx.y*16 + ty, col = blockIdx.x*16 + tx;
    const float *Xb[2], *Yb[2]; const int *Xp[2], *Yp[2]; int npair = 1;
    Xb[1]=0; Yb[1]=0; Xp[0]=0; Yp[0]=0; Xp[1]=0; Yp[1]=0;
    switch(w){
        case 0: Xb[0]=z1; Yb[0]=z1; Xb[1]=z2; Yb[1]=z2; npair=2; break;
        case 1: Xb[0]=z1; Yb[0]=z1; Yp[0]=p1; Xb[1]=z2; Yb[1]=z2; Yp[1]=p2; npair=2; break;
        case 2: Xb[0]=z2; Yb[0]=z2; Xp[0]=p2; Yp[0]=p2; break;
        case 3: Xb[0]=z2; Yb[0]=z2; Xp[0]=p2; break;
        default:Xb[0]=z1; Yb[0]=z2; break;
    }
    double acc = 0.0;
    for (int p = 0; p < npair; p++){
        const float* X = Xb[p]; const float* Y = Yb[p];
        int xr = blockIdx.y*16 + ty; if (Xp[p]) xr = Xp[p][xr];
        int yr = blockIdx.x*16 + ty; if (Yp[p]) yr = Yp[p][yr];
        for (int c = 0; c < Dd; c += 16){
            __syncthreads();
            Xs[ty][tx] = X[xr*Dd + c + tx];
            Ys[ty][tx] = Y[yr*Dd + c + tx];
            __syncthreads();
            #pragma unroll
            for (int t = 0; t < 16; t++){
                float d = Xs[ty][t] - Ys[tx][t];
                acc += (double)d * (double)d;
            }
        }
    }
    int o = row*N + col;
    if (w == 0){
        #pragma unroll
        for (int s = 0; s < 4; s++){
            double v = exp(-inv2s2_of(s)*acc);
            if (row == col) v += 1.0e-3;
            S0[(size_t)(4+s)*N*N + o] = v;
        }
    } else if (w == 1){
        #pragma unroll
        for (int s = 0; s < 4; s++){
            double v = exp(-inv2s2_of(s)*acc);
            v += __shfl_down(v, 8, 16);
            v += __shfl_down(v, 4, 16);
            v += __shfl_down(v, 2, 16);
            v += __shfl_down(v, 1, 16);
            if (tx == 0) bpart[((size_t)s*N + row)*16 + blockIdx.x] = v;
        }
    } else if (w == 2){
        #pragma unroll
        for (int s = 0; s < 4; s++){
            double v = exp(-inv2s2_of(s)*acc);
            if (row == col) v += 1.0e-3;
            S0[(size_t)s*N*N + o] = v;
        }
    } else if (w == 3){
        #pragma unroll
        for (int s = 0; s < 4; s++) M4[s*N*N + o] = (float)exp(-inv2s2_of(s)*acc);
    } else {
        #pragma unroll
        for (int s = 0; s < 4; s++) U4[s*N*N + o] = (float)exp(-inv2s2_of(s)*acc);
    }
}

// ---------------- B = M * U^T (f32 in, f64 accum/out) ----------------
__global__ void k_gemm_nt(const float* __restrict__ M4, const float* __restrict__ U4,
                          double* __restrict__ Bmat){
    __shared__ float Ms[32][33], Us[32][33];
    int tx = threadIdx.x, ty = threadIdx.y;
    int tid = ty*16 + tx;
    int s = blockIdx.z;
    const float* Mp = M4 + s*N*N;
    const float* Up = U4 + s*N*N;
    double* Bp = Bmat + s*N*N;
    int bj = blockIdx.y*32, bi = blockIdx.x*32;
    double a00=0, a01=0, a10=0, a11=0;
    for (int kc = 0; kc < N; kc += 32){
        __syncthreads();
        #pragma unroll
        for (int l = 0; l < 4; l++){
            int e = tid + l*256; int r = e >> 5, c = e & 31;
            Ms[r][c] = Mp[(bj+r)*N + kc + c];
            Us[r][c] = Up[(bi+r)*N + kc + c];
        }
        __syncthreads();
        #pragma unroll
        for (int k = 0; k < 32; k++){
            float x0 = Ms[2*ty][k], x1 = Ms[2*ty+1][k];
            float y0 = Us[2*tx][k], y1 = Us[2*tx+1][k];
            a00 += (double)x0*y0; a01 += (double)x0*y1;
            a10 += (double)x1*y0; a11 += (double)x1*y1;
        }
    }
    Bp[(bj+2*ty  )*N + bi+2*tx  ] = a00;
    Bp[(bj+2*ty  )*N + bi+2*tx+1] = a01;
    Bp[(bj+2*ty+1)*N + bi+2*tx  ] = a10;
    Bp[(bj+2*ty+1)*N + bi+2*tx+1] = a11;
}

// ---- pivot0: invert S(0:64,0:64) per matrix -> Pg0 = inv; also zero dsum ----
__global__ void k_piv0(const double* __restrict__ S0, double* __restrict__ Pg0,
                       double* __restrict__ dsum){
    __shared__ double pool[6336];
    double* T = pool;                                  // [64][66]
    double (*P32)[33] = (double(*)[33])(pool + 4224);
    double* C32 = pool + 5280;
    int mat = blockIdx.x, tid = threadIdx.x;
    if (mat == 0) dsum[tid] = 0.0;
    const double* S = S0 + (size_t)mat*65536;
    #pragma unroll
    for (int l = 0; l < 16; l++){
        int e = tid + l*256;
        T[(e>>6)*66 + (e&63)] = S[(size_t)(e>>6)*N + (e&63)];
    }
    __syncthreads();
    inv64(T, P32, C32, tid);
    double* Pd = Pg0 + (size_t)mat*4096;
    #pragma unroll
    for (int l = 0; l < 16; l++){
        int e = tid + l*256;
        Pd[e] = -T[(e>>6)*66 + (e&63)];     // P = inv = -(swept)
    }
}

// ====== blocked f64 GJ inversion, BS=64, 4 wide ping-pong steps ==============
// grid 424 = 53 tasks x 8 mats (mat=b&7). 256 threads. Tasks:
//  t<36: trailing tile (I,J) in 3x3 non-pivot grid, subtile (a,b2) 32x32:
//        F -= sum_m E_I(a,m)*C_J(b2,m)^T, C_J(b2,m)=sum_h E_J(b2,h)*P(h,m).
//  t 36..47: colrow tile i, subtile: C_i(a,b2) -> dst col + row(=C^T).
//  t 48..51: dst pivot tile subtile <- -P.
//  t==52 (k<3): prep: recompute next pivot tile (4 subtiles), inv64 -> PgD.
// All 16 dst tiles written each step (ping-pong; src never modified).
__global__ void k_step64(const double* __restrict__ Ssrc, double* __restrict__ Sdst,
                         const double* __restrict__ PgS, double* __restrict__ PgD, int k){
    __shared__ double pool[6336];
    double (*Pl)[33] = (double(*)[33])(pool);
    double (*EJ)[33] = (double(*)[33])(pool + 1056);
    double (*Cl)[33] = (double(*)[33])(pool + 2112);
    double (*El)[33] = (double(*)[33])(pool + 3168);
    double* T = pool;                                  // alias (prep, after)
    double (*P32)[33] = (double(*)[33])(pool + 4224);
    double* C32 = pool + 5280;
    int b = blockIdx.x;
    int mat = b & 7;
    int t = b >> 3;
    const double* S = Ssrc + (size_t)mat*65536;
    double* D = Sdst + (size_t)mat*65536;
    const double* Pp = PgS + (size_t)mat*4096;
    int tid = threadIdx.x;
    int Kb = k*64;
    int pr = tid >> 4, pc = tid & 15;
    int r0 = 2*pr, c0 = 2*pc;
    // stage a 32x32 chunk of src S
    auto stageS = [&](double (*buf)[33], int rb, int cb){
        #pragma unroll
        for (int l = 0; l < 4; l++){
            int e = tid + l*256; int r = e >> 5, c = e & 31;
            buf[r][c] = S[(size_t)(rb + r)*N + cb + c];
        }
    };
    auto stageP = [&](double (*buf)[33], int h, int m){
        #pragma unroll
        for (int l = 0; l < 4; l++){
            int e = tid + l*256; int r = e >> 5, c = e & 31;
            buf[r][c] = Pp[(h*32 + r)*64 + m*32 + c];
        }
    };
    auto fmap = [&](int i){ return ((i < k) ? i : i + 1) * 64; };

    if (t < 36){
        int q = t >> 2, sub = t & 3;
        int I = q / 3, J = q % 3;
        int a = sub >> 1, b2 = sub & 1;
        int GI = fmap(I) + a*32, GJ = fmap(J) + b2*32;
        double f00 = S[(size_t)(GI+r0)*N + GJ+c0];
        double f01 = S[(size_t)(GI+r0)*N + GJ+c0+1];
        double f10 = S[(size_t)(GI+r0+1)*N + GJ+c0];
        double f11 = S[(size_t)(GI+r0+1)*N + GJ+c0+1];
        for (int m = 0; m < 2; m++){
            double ce[4] = {0,0,0,0};
            for (int h = 0; h < 2; h++){
                __syncthreads();
                stageS(EJ, fmap(J) + b2*32, Kb + h*32);
                stageP(Pl, h, m);
                __syncthreads();
                #pragma unroll
                for (int l = 0; l < 4; l++){
                    int e = tid + l*256; int r = e >> 5, c = e & 31;
                    double acc = 0.0;
                    #pragma unroll
                    for (int kk = 0; kk < 32; kk++) acc += EJ[r][kk] * Pl[kk][c];
                    ce[l] += acc;
                }
            }
            __syncthreads();
            #pragma unroll
            for (int l = 0; l < 4; l++){
                int e = tid + l*256; Cl[e>>5][e&31] = ce[l];
            }
            stageS(El, fmap(I) + a*32, Kb + m*32);
            __syncthreads();
            #pragma unroll
            for (int kk = 0; kk < 32; kk++){
                double e0 = El[r0][kk],   e1 = El[r0+1][kk];
                double b0 = Cl[c0][kk],   b1 = Cl[c0+1][kk];
                f00 -= e0*b0; f01 -= e0*b1;
                f10 -= e1*b0; f11 -= e1*b1;
            }
        }
        double* Dp = D + (size_t)(GI + r0)*N + GJ + c0;
        Dp[0] = f00; Dp[1] = f01; Dp[N] = f10; Dp[N+1] = f11;
    } else if (t < 48){
        int tt = t - 36;
        int i = tt >> 2, sub = tt & 3;
        int a = sub >> 1, b2 = sub & 1;
        int Gi = fmap(i);
        double ce[4] = {0,0,0,0};
        for (int h = 0; h < 2; h++){
            __syncthreads();
            stageS(EJ, Gi + a*32, Kb + h*32);
            stageP(Pl, h, b2);
            __syncthreads();
            #pragma unroll
            for (int l = 0; l < 4; l++){
                int e = tid + l*256; int r = e >> 5, c = e & 31;
                double acc = 0.0;
                #pragma unroll
                for (int kk = 0; kk < 32; kk++) acc += EJ[r][kk] * Pl[kk][c];
                ce[l] += acc;
            }
        }
        __syncthreads();
        #pragma unroll
        for (int l = 0; l < 4; l++){
            int e = tid + l*256; Cl[e>>5][e&31] = ce[l];
        }
        __syncthreads();
        #pragma unroll
        for (int l = 0; l < 4; l++){
            int e = tid + l*256; int r = e >> 5, c = e & 31;
            D[(size_t)(Gi + a*32 + r)*N + Kb + b2*32 + c] = Cl[r][c];   // col
        }
        #pragma unroll
        for (int l = 0; l < 4; l++){
            int e = tid + l*256; int cc = e >> 5, rr = e & 31;
            D[(size_t)(Kb + b2*32 + cc)*N + Gi + a*32 + rr] = Cl[rr][cc]; // row=C^T
        }
    } else if (t < 52){
        int sub = t - 48;
        int a = sub >> 1, b2 = sub & 1;
        #pragma unroll
        for (int l = 0; l < 4; l++){
            int e = tid + l*256; int r = e >> 5, c = e & 31;
            D[(size_t)(Kb + a*32 + r)*N + Kb + b2*32 + c] = -Pp[(a*32 + r)*64 + b2*32 + c];
        }
    } else {
        if (k >= 3) return;
        // prep: recompute next pivot tile (trailing I=J=k) into regs, inv64
        int GIb = fmap(k);                 // = (k+1)*64
        double fac[4][4];
        for (int sub = 0; sub < 4; sub++){
            int a = sub >> 1, b2 = sub & 1;
            int GI = GIb + a*32, GJ = GIb + b2*32;
            fac[sub][0] = S[(size_t)(GI+r0)*N + GJ+c0];
            fac[sub][1] = S[(size_t)(GI+r0)*N + GJ+c0+1];
            fac[sub][2] = S[(size_t)(GI+r0+1)*N + GJ+c0];
            fac[sub][3] = S[(size_t)(GI+r0+1)*N + GJ+c0+1];
            for (int m = 0; m < 2; m++){
                double ce[4] = {0,0,0,0};
                for (int h = 0; h < 2; h++){
                    __syncthreads();
                    stageS(EJ, GIb + b2*32, Kb + h*32);
                    stageP(Pl, h, m);
                    __syncthreads();
                    #pragma unroll
                    for (int l = 0; l < 4; l++){
                        int e = tid + l*256; int r = e >> 5, c = e & 31;
                        double acc = 0.0;
                        #pragma unroll
                        for (int kk = 0; kk < 32; kk++) acc += EJ[r][kk] * Pl[kk][c];
                        ce[l] += acc;
                    }
                }
                __syncthreads();
                #pragma unroll
                for (int l = 0; l < 4; l++){
                    int e = tid + l*256; Cl[e>>5][e&31] = ce[l];
                }
                stageS(El, GIb + a*32, Kb + m*32);
                __syncthreads();
                #pragma unroll
                for (int kk = 0; kk < 32; kk++){
                    double e0 = El[r0][kk],   e1 = El[r0+1][kk];
                    double b0 = Cl[c0][kk],   b1 = Cl[c0+1][kk];
                    fac[sub][0] -= e0*b0; fac[sub][1] -= e0*b1;
                    fac[sub][2] -= e1*b0; fac[sub][3] -= e1*b1;
                }
                __syncthreads();
            }
        }
        // fac -> T (overlaps staging buffers; all staging done)
        for (int sub = 0; sub < 4; sub++){
            int a = sub >> 1, b2 = sub & 1;
            T[(a*32+r0  )*66 + b2*32+c0  ] = fac[sub][0];
            T[(a*32+r0  )*66 + b2*32+c0+1] = fac[sub][1];
            T[(a*32+r0+1)*66 + b2*32+c0  ] = fac[sub][2];
            T[(a*32+r0+1)*66 + b2*32+c0+1] = fac[sub][3];
        }
        __syncthreads();
        inv64(T, P32, C32, tid);
        double* Pd = PgD + (size_t)mat*4096;
        #pragma unroll
        for (int l = 0; l < 16; l++){
            int e = tid + l*256;
            Pd[e] = -T[(e>>6)*66 + (e&63)];
        }
    }
}

// ---- fused: X=G*B (f64, looped over sigma), relu(avg) colsums -> dsum;
// ---- extra row (y==8, x<4): numerator solve rnum[s] = Gnum*b (col-major).
__global__ void k_xl(const double* __restrict__ Sfin, const double* __restrict__ Bmat,
                     double* __restrict__ dsum, const double* __restrict__ bpart,
                     float* __restrict__ rnum){
    __shared__ double Gs[32][33], Bs[32][33];
    __shared__ double cp[16][33];
    __shared__ double bsh[256];
    int tx = threadIdx.x, ty = threadIdx.y;
    int tid = ty*16 + tx;
    if (blockIdx.y == 8){
        if (blockIdx.x >= 4) return;
        int s = blockIdx.x, j = tid;
        const double* Sn = Sfin + (size_t)(4+s)*N*N;   // Gnum = -Sn (symmetric)
        const double* bp = bpart + (size_t)s*N*16;
        double acc = 0;
        #pragma unroll
        for (int t = 0; t < 16; t++) acc += bp[j*16 + t];
        bsh[j] = acc;
        __syncthreads();
        double y = 0;
        for (int k = 0; k < N; k++) y -= Sn[(size_t)k*N + j] * bsh[k];
        rnum[s*N + j] = (float)y;
        return;
    }
    int bj = blockIdx.y*32, bi = blockIdx.x*32;
    int r0 = bj+2*ty, c0 = bi+2*tx;
    double s00=0, s01=0, s10=0, s11=0;
    for (int s = 0; s < 4; s++){
        const double* Sp = Sfin + (size_t)s*N*N;
        const double* Bp = Bmat + (size_t)s*N*N;
        double a00=0, a01=0, a10=0, a11=0;
        for (int kc = 0; kc < N; kc += 32){
            __syncthreads();
            #pragma unroll
            for (int l = 0; l < 4; l++){
                int e = tid + l*256; int r = e >> 5, c = e & 31;
                Gs[r][c] = -Sp[(size_t)(bj+r)*N + kc + c];
                Bs[r][c] = Bp[(size_t)(kc+r)*N + bi + c];
            }
            __syncthreads();
            #pragma unroll
            for (int k = 0; k < 32; k++){
                double x0 = Gs[2*ty][k], x1 = Gs[2*ty+1][k];
                double y0 = Bs[k][2*tx], y1 = Bs[k][2*tx+1];
                a00 += x0*y0; a01 += x0*y1;
                a10 += x1*y0; a11 += x1*y1;
            }
        }
        s00 += a00; s01 += a01; s10 += a10; s11 += a11;
    }
    // relu of sigma-average; match f32 pipeline by casting to f32 first
    double v00 = (double)fmaxf((float)(0.25*s00), 0.f);
    double v01 = (double)fmaxf((float)(0.25*s01), 0.f);
    double v10 = (double)fmaxf((float)(0.25*s10), 0.f);
    double v11 = (double)fmaxf((float)(0.25*s11), 0.f);
    __syncthreads();
    cp[ty][2*tx]   = v00 + v10;
    cp[ty][2*tx+1] = v01 + v11;
    __syncthreads();
    if (tid < 32){
        double ssum = 0;
        #pragma unroll
        for (int t = 0; t < 16; t++) ssum += cp[t][tid];
        atomicAdd(&dsum[bi + tid], ssum);
    }
}

// ---------------- final loss ----------------
__global__ void k_loss2(const double* __restrict__ dsum, const float* __restrict__ rnum,
                        float* __restrict__ out){
    __shared__ double red[256];
    int i = threadIdx.x;
    double denum = dsum[i] + (double)N * 1.0e-3;
    float ravg = 0.25f*(rnum[0*N+i] + rnum[1*N+i] + rnum[2*N+i] + rnum[3*N+i]);
    double rn = (double)fmaxf(ravg, 0.f) + 1.0e-3;
    red[i] = log(rn) + log(denum);
    __syncthreads();
    for (int st = 128; st > 0; st >>= 1){
        if (i < st) red[i] += red[i + st];
        __syncthreads();
    }
    if (i == 0) out[0] = (float)red[0];
}

extern "C" void kernel_launch(void* const* d_in, const int* in_sizes, int n_in,
                              void* d_out, int out_size, void* d_ws, size_t ws_size,
                              hipStream_t stream) {
    (void)in_sizes; (void)n_in; (void)out_size; (void)ws_size;
    const float* z1 = (const float*)d_in[0];
    const float* z2 = (const float*)d_in[1];
    const int*   p1 = (const int*)d_in[2];
    const int*   p2 = (const int*)d_in[3];
    float* out = (float*)d_out;

    char* w = (char*)d_ws;
    size_t o = 0;
    auto carve = [&](size_t bytes) -> char* {
        char* p = w + o;
        o += (bytes + 255) & ~(size_t)255;
        return p;
    };
    double* bpart = (double*)carve((size_t)4*N*16*sizeof(double));
    double* dsum  = (double*)carve((size_t)N*sizeof(double));
    float*  M4    = (float*) carve((size_t)4*N*N*sizeof(float));
    float*  U4    = (float*) carve((size_t)4*N*N*sizeof(float));
    double* Bmat  = (double*)carve((size_t)4*N*N*sizeof(double));
    float*  rnum  = (float*) carve((size_t)4*N*sizeof(float));
    double* S0    = (double*)carve((size_t)8*N*N*sizeof(double));  // ping
    double* S1    = (double*)carve((size_t)8*N*N*sizeof(double));  // pong
    double* Pg0   = (double*)carve((size_t)8*64*64*sizeof(double));
    double* Pg1   = (double*)carve((size_t)8*64*64*sizeof(double));

    k_dist<<<dim3(16,16,5), dim3(16,16), 0, stream>>>(z1, z2, p1, p2,
                                                      S0, M4, U4, bpart);
    k_gemm_nt<<<dim3(8,8,4), dim3(16,16), 0, stream>>>(M4, U4, Bmat);
    k_piv0<<<dim3(8), dim3(256), 0, stream>>>(S0, Pg0, dsum);
    for (int k = 0; k < 4; k++){
        double* src = (k & 1) ? S1 : S0;
        double* dst = (k & 1) ? S0 : S1;
        double* ps  = (k & 1) ? Pg1 : Pg0;
        double* pd  = (k & 1) ? Pg0 : Pg1;
        k_step64<<<dim3(424), dim3(256), 0, stream>>>(src, dst, ps, pd, k);
    }
    // after k=3 (odd count): final swept matrices in S0
    k_xl<<<dim3(8,9), dim3(16,16), 0, stream>>>(S0, Bmat, dsum, bpart, rnum);
    k_loss2<<<dim3(1), dim3(256), 0, stream>>>(dsum, rnum, out);
}